// Round 12
// baseline (353.777 us; speedup 1.0000x reference)
//
#include <hip/hip_runtime.h>
#include <math.h>

#define BB 256
#define SS 30
#define CC 62
#define LL 169
#define OG 64
#define OH 64
#define KK1 64
#define KK2 32
#define KK3 14
#define FLEN 108     // 64+32+14-2
#define NT 15        // tiles per persistent block
#define NSTEP (3 * NT)

typedef __attribute__((ext_vector_type(8))) short s16x8;
typedef __attribute__((ext_vector_type(4))) float f32x4;

__device__ __forceinline__ unsigned short f2bf(float f) {
    unsigned u = __float_as_uint(f);
    u += 0x7fffu + ((u >> 16) & 1u);        // RTNE
    return (unsigned short)(u >> 16);
}
__device__ __forceinline__ float bflo(unsigned v) { return __uint_as_float(v << 16); }
__device__ __forceinline__ float bfhi(unsigned v) { return __uint_as_float(v & 0xffff0000u); }

__device__ __forceinline__ void gload_lds4(const void* g, void* l) {
    __builtin_amdgcn_global_load_lds(
        (const __attribute__((address_space(1))) void*)g,
        (__attribute__((address_space(3))) void*)l, 4, 0, 0);
}
__device__ __forceinline__ void gload_lds16(const void* g, void* l) {
    __builtin_amdgcn_global_load_lds(
        (const __attribute__((address_space(1))) void*)g,
        (__attribute__((address_space(3))) void*)l, 16, 0, 0);
}

// Issue one step (third of a tile, n3 dwords) into LDS buffer lb.
// CONSTANT per-wave VMEM count: every wave 4 bulk DMA16 (clamped); wave0 +2 DMA4.
// LDS mapping: step dword g lands at LDS dword (g + sh), sh = (gbase&8)>>2.
__device__ __forceinline__ void issue_step(const char* gb, char* lb, int n3, int tid) {
    int shb = (int)((size_t)gb & 8);          // 0 or 8 bytes
    int sh  = shb >> 2;                        // 0 or 2 dwords
    int q   = n3 - sh;
    int nch = q >> 2;                          // bulk 16B chunks
    int rem = q & 3;                           // 0 or 2
    int wofs = (tid >> 6) * 1024;
    #pragma unroll
    for (int r = 0; r < 4; ++r) {
        int cc = r * 256 + tid;
        if (cc > nch - 1) cc = nch - 1;        // clamp: duplicate last chunk (slack slots)
        gload_lds16(gb + shb + (size_t)cc * 16, lb + 2 * shb + r * 4096 + wofs);
    }
    if (tid < 2) {                             // wave0 only: exactly 2 aux DMA4s
        if (sh) gload_lds4(gb + 4 * tid, lb + 8);           // head g=0,1 -> slots 2,3
        else    gload_lds4(gb + 4 * tid, lb + 16400);       // dummy -> scratch
        if (rem) {
            int g0 = sh + 4 * nch;
            gload_lds4(gb + 4 * (g0 + tid), lb + 4 * (g0 + sh));
        } else {
            gload_lds4(gb + 4 * tid, lb + 16408);           // dummy -> scratch
        }
    }
}

// ---------------- setup stage 1 (1 block): weights prep + Bm ----------------
__global__ __launch_bounds__(1024) void k_setup1(
        const float* __restrict__ dw1, const float* __restrict__ dw1b,
        const float* __restrict__ pw1, const float* __restrict__ pw1b,
        const float* __restrict__ dw2, const float* __restrict__ dw2b,
        const float* __restrict__ pw2, const float* __restrict__ pw2b,
        const float* __restrict__ dw3, const float* __restrict__ dw3b,
        const float* __restrict__ pw3, const float* __restrict__ pw3b,
        const float* __restrict__ Wr, const float* __restrict__ Wrb, const float* __restrict__ br,
        const float* __restrict__ Wu, const float* __restrict__ Wub, const float* __restrict__ bu,
        const float* __restrict__ Wc, const float* __restrict__ Wcb, const float* __restrict__ bc,
        float* __restrict__ Bmg, float* __restrict__ WtAll,
        float* __restrict__ bias192, float* __restrict__ beff) {
    __shared__ float g23[CC * KK3];
    __shared__ float Am[CC * 45];
    __shared__ float by2[CC], vals[CC];
    int tid = threadIdx.x;

    for (int idx = tid; idx < OG * 192; idx += 1024) {
        int i = idx / 192, q = idx - i * 192;
        int gate = q >> 6, f = q & 63;
        const float* W = gate == 0 ? Wr : (gate == 1 ? Wu : Wc);
        WtAll[idx] = W[f * (OG + OH) + i];
    }
    if (tid < 192) {
        int gate = tid >> 6, f = tid & 63;
        const float* Wb = gate == 0 ? Wrb : (gate == 1 ? Wub : Wcb);
        const float* bb = gate == 0 ? br  : (gate == 1 ? bu  : bc);
        bias192[tid] = Wb[f] + bb[f];
    }
    for (int idx = tid; idx < CC * KK3; idx += 1024) {
        int c1 = idx / KK3, k3 = idx - c1 * KK3;
        float s = 0.f;
        for (int c2 = 0; c2 < CC; ++c2)
            s += pw3[61 * CC + c2] * pw2[c2 * CC + c1] * dw3[c2 * KK3 + k3];
        g23[idx] = s;
    }
    if (tid < CC) {
        int c1 = tid;
        float bz1 = pw1b[c1];
        for (int c0 = 0; c0 < CC; ++c0) bz1 += pw1[c1 * CC + c0] * dw1b[c0];
        float s2 = 0.f;
        for (int k = 0; k < KK2; ++k) s2 += dw2[c1 * KK2 + k];
        by2[c1] = dw2b[c1] + bz1 * s2;
    }
    __syncthreads();
    if (tid < CC) {
        int c2 = tid;
        float bz2 = pw2b[c2];
        for (int c1 = 0; c1 < CC; ++c1) bz2 += pw2[c2 * CC + c1] * by2[c1];
        float s3 = 0.f;
        for (int k = 0; k < KK3; ++k) s3 += dw3[c2 * KK3 + k];
        vals[c2] = pw3[61 * CC + c2] * (dw3b[c2] + bz2 * s3);
    }
    for (int idx = tid; idx < CC * 45; idx += 1024) {
        int c1 = idx / 45, m = idx - c1 * 45;
        int k2lo = max(0, m - (KK3 - 1));
        int k2hi = min(KK2 - 1, m);
        float s = 0.f;
        for (int k2 = k2lo; k2 <= k2hi; ++k2)
            s += dw2[c1 * KK2 + k2] * g23[c1 * KK3 + (m - k2)];
        Am[idx] = s;
    }
    __syncthreads();
    if (tid == 0) {
        float s = pw3b[61];
        for (int c2 = 0; c2 < CC; ++c2) s += vals[c2];
        *beff = s;
    }
    for (int idx = tid; idx < CC * 45; idx += 1024) {
        int c0 = idx / 45, m = idx - c0 * 45;
        float s = 0.f;
        for (int c1 = 0; c1 < CC; ++c1) s += pw1[c1 * CC + c0] * Am[c1 * 45 + m];
        Bmg[idx] = s;
    }
}

// ---------------- setup stage 2 (64 blocks): Ftb[o][c0] ----------------
__global__ __launch_bounds__(128) void k_setupF(
        const float* __restrict__ Bmg, const float* __restrict__ dw1,
        unsigned short* __restrict__ Ftb) {
    __shared__ float Bl[45];
    int c0 = blockIdx.x;
    int o = threadIdx.x;
    if (c0 < CC && o < 45) Bl[o] = Bmg[c0 * 45 + o];
    __syncthreads();
    if (o >= 112) return;
    float s = 0.f;
    if (c0 < CC && o < FLEN) {
        int mlo = max(0, o - (KK1 - 1));
        int mhi = min(44, o);
        for (int m = mlo; m <= mhi; ++m)
            s += Bl[m] * dw1[c0 * KK1 + (o - m)];
    }
    Ftb[o * 64 + c0] = f2bf(s);
}

// ---------------- main: persistent block, NT tiles, pipelined DMA ----------------
__global__ __launch_bounds__(256, 2) void k_main(
        const float* __restrict__ x, const float* __restrict__ adj,
        const unsigned short* __restrict__ Ftb, const float* __restrict__ beff_p,
        float* __restrict__ wxb) {
    __shared__ __align__(16) char fbuf[2][16416];           // 32832 B (two step buffers)
    __shared__ __align__(16) unsigned short xT[176 * 64];   // 22528 B swizzled [l][c] bf16
    __shared__ float dacc[4][64];
    __shared__ float adjt[64];

    int tid = threadIdx.x;
    int lane = tid & 63, wid = tid >> 6;
    int col = lane & 15, rb4 = lane >> 4;
    unsigned* xTu = (unsigned*)xT;

    const int off3[3]  = {0, 13520, 28392};   // byte offsets of thirds within a tile
    const int n3tab[3] = {3380, 3718, 3380};  // dwords per third (c 0..19 / 20..41 / 42..61)
    const int cp0tab[3] = {0, 10, 21};
    const int ncptab[3] = {10, 11, 10};

    const char* xblk = (const char*)x + (size_t)blockIdx.x * NT * 41912;

    // prologue: zero xT (incl. pads) + dacc; preload aux + A-fragments
    for (int i = tid; i < 176 * 32; i += 256) xTu[i] = 0;
    ((float*)dacc)[tid & 255] = 0.f;
    float be = *beff_p;
    float arow = (tid < CC) ? adj[61 * CC + tid] : 0.f;
    const unsigned short* ap0 = Ftb + ((wid * 16 + col) * 64 + rb4 * 8);
    s16x8 pa0 = *(const s16x8*)ap0;
    s16x8 pa1 = *(const s16x8*)(ap0 + 32);
    int mt2c = wid + 4 < 7 ? wid + 4 : 6;
    const unsigned short* ap1 = Ftb + ((mt2c * 16 + col) * 64 + rb4 * 8);
    s16x8 pb0 = *(const s16x8*)ap1;
    s16x8 pb1 = *(const s16x8*)(ap1 + 32);

    // issue DMA for steps 0 and 1
    issue_step(xblk + off3[0], fbuf[0], n3tab[0], tid);
    issue_step(xblk + off3[1], fbuf[1], n3tab[1], tid);
    asm volatile("s_waitcnt lgkmcnt(0)" ::: "memory");
    __builtin_amdgcn_sched_barrier(0);

    int kb = rb4 * 16;
    int xr = (lane & 7) << 4;
    int jc = col - rb4 * 4;

    for (int k = 0; k < NSTEP; ++k) {
        int th = k % 3;
        int t = k / 3;
        // wait: DMA(k) drained (DMA(k+1) stays in flight)
        if (k == NSTEP - 1)      { asm volatile("s_waitcnt vmcnt(0)" ::: "memory"); }
        else if (wid == 0)       { asm volatile("s_waitcnt vmcnt(6)" ::: "memory"); }
        else                     { asm volatile("s_waitcnt vmcnt(4)" ::: "memory"); }
        __builtin_amdgcn_sched_barrier(0);
        __builtin_amdgcn_s_barrier();

        // transpose third th of tile t: fbuf[k&1] (f32) -> xT (bf16, swizzled)
        {
            const char* gb = xblk + (size_t)t * 41912 + off3[th];
            int sh = ((int)((size_t)gb & 8)) >> 2;
            const unsigned* fb = (const unsigned*)fbuf[k & 1];
            int ncp = ncptab[th], cp0 = cp0tab[th];
            for (int it = tid; it < 16 * 169; it += 256) {
                int cpL = it & 15, l = it >> 4;
                if (cpL < ncp) {
                    int glo = (2 * cpL) * 169 + l;
                    unsigned lo = fb[glo + sh];
                    unsigned hi = fb[glo + 169 + sh];
                    unsigned v = (unsigned)f2bf(__uint_as_float(lo))
                               | ((unsigned)f2bf(__uint_as_float(hi)) << 16);
                    xTu[(l * 32 + cp0 + cpL) ^ ((l & 7) << 2)] = v;
                }
            }
        }
        asm volatile("s_waitcnt lgkmcnt(0)" ::: "memory");
        __builtin_amdgcn_sched_barrier(0);
        __builtin_amdgcn_s_barrier();

        // issue DMA(k+2) into the just-freed buffer; flies under compute below
        if (k + 2 < NSTEP) {
            int k2 = k + 2, th2 = k2 % 3, t2 = k2 / 3;
            issue_step(xblk + (size_t)t2 * 41912 + off3[th2], fbuf[k & 1], n3tab[th2], tid);
        }

        if (th == 2) {
            // ---- MFMA band on full xT ----
            f32x4 zacc[5];
            #pragma unroll
            for (int d = 0; d < 5; ++d) zacc[d] = (f32x4){0.f, 0.f, 0.f, 0.f};
            #pragma unroll
            for (int h = 0; h < 2; ++h) {
                int mt = wid + 4 * h;
                if (mt < 7) {
                    s16x8 a0 = h == 0 ? pa0 : pb0;
                    s16x8 a1 = h == 0 ? pa1 : pb1;
                    #pragma unroll
                    for (int d = 0; d < 5; ++d) {
                        int nt = mt + d;
                        int bbyte = ((nt * 16 + col) * 128 + kb) ^ xr;
                        s16x8 b0 = *(const s16x8*)((const char*)xT + bbyte);
                        s16x8 b1 = *(const s16x8*)((const char*)xT + bbyte + 64);
                        zacc[d] = __builtin_amdgcn_mfma_f32_16x16x32_bf16(a0, b0, zacc[d], 0, 0, 0);
                        zacc[d] = __builtin_amdgcn_mfma_f32_16x16x32_bf16(a1, b1, zacc[d], 0, 0, 0);
                    }
                }
            }
            #pragma unroll
            for (int d = 0; d < 5; ++d) {
                #pragma unroll
                for (int r = 0; r < 4; ++r) {
                    int j = 16 * d + jc - r;
                    if ((unsigned)j < 62u) atomicAdd(&dacc[rb4][j], zacc[d][r]);
                }
            }
            asm volatile("s_waitcnt lgkmcnt(0)" ::: "memory");
            __builtin_amdgcn_sched_barrier(0);
            __builtin_amdgcn_s_barrier();

            // sigmoid + re-zero dacc for next tile
            if (tid < CC) {
                float dv = dacc[0][tid] + dacc[1][tid] + dacc[2][tid] + dacc[3][tid];
                adjt[tid] = 1.f / (1.f + __expf(-(dv + be + arow)));
                dacc[0][tid] = 0.f; dacc[1][tid] = 0.f;
                dacc[2][tid] = 0.f; dacc[3][tid] = 0.f;
            }
            asm volatile("s_waitcnt lgkmcnt(0)" ::: "memory");
            __builtin_amdgcn_sched_barrier(0);
            __builtin_amdgcn_s_barrier();

            // wx from xT bf16 + adjt -> global
            if (tid < 176) {
                float s = 0.f;
                if (tid < LL) {
                    int xorv = (tid & 7) << 2;
                    #pragma unroll
                    for (int m = 0; m < 31; ++m) {
                        unsigned v = xTu[(tid * 32 + m) ^ xorv];
                        s += adjt[2 * m] * bflo(v) + adjt[2 * m + 1] * bfhi(v);
                    }
                }
                wxb[((size_t)(blockIdx.x * NT + t)) * 176 + tid] = s;
            }
            __builtin_amdgcn_s_barrier();   // protect xT before next tile's transpose
        }
    }
}

// ---------------- fused G + gates: 8 bt per block ----------------
__global__ __launch_bounds__(256) void k_gg(
        const float* __restrict__ wxb, const float* __restrict__ gcnw,
        const float* __restrict__ gcnb, const float* __restrict__ WtAll,
        const float* __restrict__ bias192, float* __restrict__ gates) {
    __shared__ float wxl[8 * 176];
    __shared__ float Gl[8 * 64];
    int bt0 = blockIdx.x * 8;
    int tid = threadIdx.x;
    const float* src = wxb + (size_t)bt0 * 176;
    for (int i = tid; i < 8 * 176; i += 256) wxl[i] = src[i];
    __syncthreads();
    #pragma unroll
    for (int rep = 0; rep < 2; ++rep) {
        int i = rep * 256 + tid;
        int bl = i >> 6, f = i & 63;
        float s = gcnb[f];
        const float* wr = wxl + bl * 176;
        #pragma unroll 13
        for (int l = 0; l < LL; ++l) s += wr[l] * gcnw[l * OG + f];
        Gl[i] = s;
    }
    __syncthreads();
    float* gout = gates + (size_t)bt0 * 192;
    #pragma unroll
    for (int rep = 0; rep < 6; ++rep) {
        int i = rep * 256 + tid;
        int bl = i / 192, q = i - bl * 192;
        const float* gr = Gl + bl * 64;
        float s = bias192[q];
        #pragma unroll 16
        for (int k = 0; k < OG; ++k) s += gr[k] * WtAll[k * 192 + q];
        gout[i] = s;
    }
}

// ---------------- sequential GRU scan over t: one block per batch row ----------------
__global__ __launch_bounds__(256) void k_scan(
        const float* __restrict__ gates,
        const float* __restrict__ Wr, const float* __restrict__ Wu, const float* __restrict__ Wc,
        float* __restrict__ out) {
    __shared__ float hl[OH], rhl[OH];
    int b = blockIdx.x;
    int tid = threadIdx.x;
    int f = tid >> 2, q = tid & 3;
    float wr[16], wu[16], wc[16];
    #pragma unroll
    for (int i = 0; i < 16; ++i) {
        int col = OG + q * 16 + i;
        wr[i] = Wr[f * (OG + OH) + col];
        wu[i] = Wu[f * (OG + OH) + col];
        wc[i] = Wc[f * (OG + OH) + col];
    }
    float h = 0.f;
    if (tid < OH) hl[tid] = 0.f;
    __syncthreads();
    for (int t = 0; t < SS; ++t) {
        const float* gp = gates + ((size_t)b * SS + t) * 192;
        float gr = gp[f];
        float gu = gp[64 + f];
        float gc = gp[128 + f];
        float rv = 0.f, uv = 0.f;
        #pragma unroll
        for (int i = 0; i < 16; ++i) {
            float hv = hl[q * 16 + i];
            rv += wr[i] * hv;
            uv += wu[i] * hv;
        }
        rv += __shfl_xor(rv, 1); rv += __shfl_xor(rv, 2);
        uv += __shfl_xor(uv, 1); uv += __shfl_xor(uv, 2);
        float r = 1.f / (1.f + __expf(-(rv + gr)));
        float u = 1.f / (1.f + __expf(-(uv + gu)));
        if (q == 0) rhl[f] = r * h;
        __syncthreads();
        float cv = 0.f;
        #pragma unroll
        for (int i = 0; i < 16; ++i) cv += wc[i] * rhl[q * 16 + i];
        cv += __shfl_xor(cv, 1); cv += __shfl_xor(cv, 2);
        float cc = tanhf(cv + gc);
        if (q == 0) {
            h = u * h + (1.f - u) * cc;
            hl[f] = h;
        }
        __syncthreads();
    }
    if (q == 0) out[b * OH + f] = h;
}

extern "C" void kernel_launch(void* const* d_in, const int* in_sizes, int n_in,
                              void* d_out, int out_size, void* d_ws, size_t ws_size,
                              hipStream_t stream) {
    const float* x    = (const float*)d_in[0];
    const float* adj  = (const float*)d_in[1];
    const float* dw1w = (const float*)d_in[2];
    const float* dw1b = (const float*)d_in[3];
    const float* pw1w = (const float*)d_in[4];
    const float* pw1b = (const float*)d_in[5];
    const float* dw2w = (const float*)d_in[6];
    const float* dw2b = (const float*)d_in[7];
    const float* pw2w = (const float*)d_in[8];
    const float* pw2b = (const float*)d_in[9];
    const float* dw3w = (const float*)d_in[10];
    const float* dw3b = (const float*)d_in[11];
    const float* pw3w = (const float*)d_in[12];
    const float* pw3b = (const float*)d_in[13];
    const float* gcnw = (const float*)d_in[14];
    const float* gcnb = (const float*)d_in[15];
    const float* Wrw  = (const float*)d_in[16];
    const float* Wrb  = (const float*)d_in[17];
    const float* Wuw  = (const float*)d_in[18];
    const float* Wub  = (const float*)d_in[19];
    const float* Wcw  = (const float*)d_in[20];
    const float* Wcb  = (const float*)d_in[21];
    const float* br   = (const float*)d_in[22];
    const float* bu   = (const float*)d_in[23];
    const float* bc   = (const float*)d_in[24];
    float* out = (float*)d_out;

    char* ws = (char*)d_ws;
    unsigned short* Ftb = (unsigned short*)(ws + 0);        // 14336 B
    float* WtAll        = (float*)(ws + 14336);             // 49152 B
    float* bias192      = (float*)(ws + 63488);             // 768 B
    float* beff         = (float*)(ws + 64256);             // 4 B
    float* Bmg          = (float*)(ws + 64320);             // 11160 B
    float* wxb          = (float*)(ws + 76800);             // 5406720 B
    float* gates        = (float*)(ws + 5483520);           // 5898240 B
    (void)ws_size; (void)in_sizes; (void)n_in; (void)out_size;

    k_setup1<<<1, 1024, 0, stream>>>(dw1w, dw1b, pw1w, pw1b, dw2w, dw2b, pw2w, pw2b,
                                     dw3w, dw3b, pw3w, pw3b,
                                     Wrw, Wrb, br, Wuw, Wub, bu, Wcw, Wcb, bc,
                                     Bmg, WtAll, bias192, beff);
    k_setupF<<<64, 128, 0, stream>>>(Bmg, dw1w, Ftb);
    k_main<<<BB * SS / NT, 256, 0, stream>>>(x, adj, Ftb, beff, wxb);
    k_gg<<<BB * SS / 8, 256, 0, stream>>>(wxb, gcnw, gcnb, WtAll, bias192, gates);
    k_scan<<<BB, 256, 0, stream>>>(gates, Wrw, Wuw, Wcw, out);
}

// Round 13
// 291.816 us; speedup vs baseline: 1.2123x; 1.2123x over previous
//
#include <hip/hip_runtime.h>
#include <math.h>

#define BB 256
#define SS 30
#define CC 62
#define LL 169
#define OG 64
#define OH 64
#define KK1 64
#define KK2 32
#define KK3 14
#define FLEN 108     // 64+32+14-2

typedef __attribute__((ext_vector_type(8))) short s16x8;
typedef __attribute__((ext_vector_type(4))) float f32x4;

__device__ __forceinline__ unsigned short f2bf(float f) {
    unsigned u = __float_as_uint(f);
    u += 0x7fffu + ((u >> 16) & 1u);        // RTNE
    return (unsigned short)(u >> 16);
}
__device__ __forceinline__ float bflo(unsigned v) { return __uint_as_float(v << 16); }
__device__ __forceinline__ float bfhi(unsigned v) { return __uint_as_float(v & 0xffff0000u); }

// ---------------- setup stage 1 (1 block): weights prep + Bm ----------------
__global__ __launch_bounds__(1024) void k_setup1(
        const float* __restrict__ dw1, const float* __restrict__ dw1b,
        const float* __restrict__ pw1, const float* __restrict__ pw1b,
        const float* __restrict__ dw2, const float* __restrict__ dw2b,
        const float* __restrict__ pw2, const float* __restrict__ pw2b,
        const float* __restrict__ dw3, const float* __restrict__ dw3b,
        const float* __restrict__ pw3, const float* __restrict__ pw3b,
        const float* __restrict__ Wr, const float* __restrict__ Wrb, const float* __restrict__ br,
        const float* __restrict__ Wu, const float* __restrict__ Wub, const float* __restrict__ bu,
        const float* __restrict__ Wc, const float* __restrict__ Wcb, const float* __restrict__ bc,
        float* __restrict__ Bmg, float* __restrict__ WtAll,
        float* __restrict__ bias192, float* __restrict__ beff) {
    __shared__ float g23[CC * KK3];
    __shared__ float Am[CC * 45];
    __shared__ float by2[CC], vals[CC];
    int tid = threadIdx.x;

    for (int idx = tid; idx < OG * 192; idx += 1024) {
        int i = idx / 192, q = idx - i * 192;
        int gate = q >> 6, f = q & 63;
        const float* W = gate == 0 ? Wr : (gate == 1 ? Wu : Wc);
        WtAll[idx] = W[f * (OG + OH) + i];
    }
    if (tid < 192) {
        int gate = tid >> 6, f = tid & 63;
        const float* Wb = gate == 0 ? Wrb : (gate == 1 ? Wub : Wcb);
        const float* bb = gate == 0 ? br  : (gate == 1 ? bu  : bc);
        bias192[tid] = Wb[f] + bb[f];
    }
    for (int idx = tid; idx < CC * KK3; idx += 1024) {
        int c1 = idx / KK3, k3 = idx - c1 * KK3;
        float s = 0.f;
        for (int c2 = 0; c2 < CC; ++c2)
            s += pw3[61 * CC + c2] * pw2[c2 * CC + c1] * dw3[c2 * KK3 + k3];
        g23[idx] = s;
    }
    if (tid < CC) {
        int c1 = tid;
        float bz1 = pw1b[c1];
        for (int c0 = 0; c0 < CC; ++c0) bz1 += pw1[c1 * CC + c0] * dw1b[c0];
        float s2 = 0.f;
        for (int k = 0; k < KK2; ++k) s2 += dw2[c1 * KK2 + k];
        by2[c1] = dw2b[c1] + bz1 * s2;
    }
    __syncthreads();
    if (tid < CC) {
        int c2 = tid;
        float bz2 = pw2b[c2];
        for (int c1 = 0; c1 < CC; ++c1) bz2 += pw2[c2 * CC + c1] * by2[c1];
        float s3 = 0.f;
        for (int k = 0; k < KK3; ++k) s3 += dw3[c2 * KK3 + k];
        vals[c2] = pw3[61 * CC + c2] * (dw3b[c2] + bz2 * s3);
    }
    for (int idx = tid; idx < CC * 45; idx += 1024) {
        int c1 = idx / 45, m = idx - c1 * 45;
        int k2lo = max(0, m - (KK3 - 1));
        int k2hi = min(KK2 - 1, m);
        float s = 0.f;
        for (int k2 = k2lo; k2 <= k2hi; ++k2)
            s += dw2[c1 * KK2 + k2] * g23[c1 * KK3 + (m - k2)];
        Am[idx] = s;
    }
    __syncthreads();
    if (tid == 0) {
        float s = pw3b[61];
        for (int c2 = 0; c2 < CC; ++c2) s += vals[c2];
        *beff = s;
    }
    for (int idx = tid; idx < CC * 45; idx += 1024) {
        int c0 = idx / 45, m = idx - c0 * 45;
        float s = 0.f;
        for (int c1 = 0; c1 < CC; ++c1) s += pw1[c1 * CC + c0] * Am[c1 * 45 + m];
        Bmg[idx] = s;
    }
}

// ---------------- setup stage 2 (64 blocks): Ftb[o][c0] ----------------
__global__ __launch_bounds__(128) void k_setupF(
        const float* __restrict__ Bmg, const float* __restrict__ dw1,
        unsigned short* __restrict__ Ftb) {
    __shared__ float Bl[45];
    int c0 = blockIdx.x;
    int o = threadIdx.x;
    if (c0 < CC && o < 45) Bl[o] = Bmg[c0 * 45 + o];
    __syncthreads();
    if (o >= 112) return;
    float s = 0.f;
    if (c0 < CC && o < FLEN) {
        int mlo = max(0, o - (KK1 - 1));
        int mhi = min(44, o);
        for (int m = mlo; m <= mhi; ++m)
            s += Bl[m] * dw1[c0 * KK1 + (o - m)];
    }
    Ftb[o * 64 + c0] = f2bf(s);
}

// ---------------- main: one block per (b,t); asm rolling-pipeline staging ----------------
#define STG_ISSUE(i, s) do {                                                   \
    const float* pA = xg + 338 * cpa[i] + l0a[i];                              \
    const float* pB = pA + 169;                                                \
    asm volatile("global_load_dwordx2 %0, %1, off" : "=v"(A0[s]) : "v"(pA));   \
    asm volatile("global_load_dwordx2 %0, %1, off" : "=v"(A1[s]) : "v"(pA + 2));\
    asm volatile("global_load_dwordx2 %0, %1, off" : "=v"(B0[s]) : "v"(pB));   \
    asm volatile("global_load_dwordx2 %0, %1, off" : "=v"(B1[s]) : "v"(pB + 2));\
} while (0)

#define STG_CONSUME(i, s, VM) do {                                             \
    asm volatile("s_waitcnt vmcnt(" VM ")"                                     \
        : "+v"(A0[s]), "+v"(A1[s]), "+v"(B0[s]), "+v"(B1[s]));                 \
    unsigned d0, d1, d2, d3;                                                   \
    asm("v_cvt_pk_bf16_f32 %0, %1, %2" : "=v"(d0)                             \
        : "v"(__uint_as_float(A0[s].x)), "v"(__uint_as_float(B0[s].x)));       \
    asm("v_cvt_pk_bf16_f32 %0, %1, %2" : "=v"(d1)                             \
        : "v"(__uint_as_float(A0[s].y)), "v"(__uint_as_float(B0[s].y)));       \
    asm("v_cvt_pk_bf16_f32 %0, %1, %2" : "=v"(d2)                             \
        : "v"(__uint_as_float(A1[s].x)), "v"(__uint_as_float(B1[s].x)));       \
    asm("v_cvt_pk_bf16_f32 %0, %1, %2" : "=v"(d3)                             \
        : "v"(__uint_as_float(A1[s].y)), "v"(__uint_as_float(B1[s].y)));       \
    int l0 = l0a[i], cp = cpa[i];                                              \
    xTu[((l0 + 0) * 32 + cp) ^ (((l0 + 0) & 7) << 2)] = d0;                    \
    xTu[((l0 + 1) * 32 + cp) ^ (((l0 + 1) & 7) << 2)] = d1;                    \
    xTu[((l0 + 2) * 32 + cp) ^ (((l0 + 2) & 7) << 2)] = d2;                    \
    xTu[((l0 + 3) * 32 + cp) ^ (((l0 + 3) & 7) << 2)] = d3;                    \
} while (0)

__global__ __launch_bounds__(256, 3) void k_main(
        const float* __restrict__ x, const float* __restrict__ adj,
        const unsigned short* __restrict__ Ftb, const float* __restrict__ beff_p,
        float* __restrict__ wxb) {
    __shared__ __align__(16) unsigned short xT[176 * 64];   // 22528 B swizzled [l][c] bf16
    __shared__ float dacc[4][4][64];                        // per-wave copies: 4096 B
    __shared__ float adjt[64];
    int bt = blockIdx.x;
    int tid = threadIdx.x;
    int lane = tid & 63, wid = tid >> 6;
    int col = lane & 15, rb4 = lane >> 4;
    unsigned* xTu = (unsigned*)xT;
    const float* xg = x + (size_t)bt * (CC * LL);

    // aux loads FIRST: their vmcnt entries are older than the pipeline's, so the
    // literal waits below remain sufficient (vmcnt waits drain oldest-first).
    float be = *beff_p;                                        // SMEM (lgkm)
    float arow = (tid < CC) ? adj[61 * CC + tid] : 0.f;        // 1 vmem
    const unsigned short* ap0 = Ftb + ((wid * 16 + col) * 64 + rb4 * 8);
    s16x8 pa0 = *(const s16x8*)ap0;
    s16x8 pa1 = *(const s16x8*)(ap0 + 32);
    int mt2c = wid + 4 < 7 ? wid + 4 : 6;
    const unsigned short* ap1 = Ftb + ((mt2c * 16 + col) * 64 + rb4 * 8);
    s16x8 pb0 = *(const s16x8*)ap1;
    s16x8 pb1 = *(const s16x8*)(ap1 + 32);
    __builtin_amdgcn_sched_barrier(0);

    // staging work decomposition: w = lg*31 + cp, lg in [0,43), cp in [0,31)
    // pair (cp): channels 2cp, 2cp+1; l0 = 4*lg (lg<42) else 165; 4 l's per step.
    uint2 A0[3], A1[3], B0[3], B1[3];
    int l0a[6], cpa[6];
    #pragma unroll
    for (int i = 0; i < 6; ++i) {
        int w = tid + i * 256; if (w > 1332) w = 1332;
        int lg = w / 31; cpa[i] = w - lg * 31;
        l0a[i] = (lg < 42) ? 4 * lg : 165;
    }
    STG_ISSUE(0, 0); STG_ISSUE(1, 1); STG_ISSUE(2, 2);
    // overlap load latency: zero pads (col 31, rows>=169) + dacc
    for (int i = tid; i < 169; i += 256) xTu[(i * 32 + 31) ^ ((i & 7) << 2)] = 0;
    for (int i = tid; i < 224; i += 256) {
        int r = 169 + (i >> 5), dd = i & 31;
        xTu[(r * 32 + dd) ^ ((r & 7) << 2)] = 0;
    }
    ((float*)dacc)[tid] = 0.f;       ((float*)dacc)[tid + 256] = 0.f;
    ((float*)dacc)[tid + 512] = 0.f; ((float*)dacc)[tid + 768] = 0.f;

    STG_CONSUME(0, 0, "8"); STG_ISSUE(3, 0);
    STG_CONSUME(1, 1, "8"); STG_ISSUE(4, 1);
    STG_CONSUME(2, 2, "8"); STG_ISSUE(5, 2);
    STG_CONSUME(3, 0, "8");
    STG_CONSUME(4, 1, "4");
    STG_CONSUME(5, 2, "0");
    __syncthreads();

    // ---- MFMA band: wave wid handles mt in {wid, wid+4}; zacc[d] accumulates ----
    f32x4 zacc[5];
    #pragma unroll
    for (int d = 0; d < 5; ++d) zacc[d] = (f32x4){0.f, 0.f, 0.f, 0.f};
    int kb = rb4 * 16;
    int xr = (lane & 7) << 4;
    #pragma unroll
    for (int h = 0; h < 2; ++h) {
        int mt = wid + 4 * h;
        if (mt < 7) {
            s16x8 a0 = h == 0 ? pa0 : pb0;
            s16x8 a1 = h == 0 ? pa1 : pb1;
            #pragma unroll
            for (int d = 0; d < 5; ++d) {
                int nt = mt + d;
                int bbyte = ((nt * 16 + col) * 128 + kb) ^ xr;
                s16x8 b0 = *(const s16x8*)((const char*)xT + bbyte);
                s16x8 b1 = *(const s16x8*)((const char*)xT + bbyte + 64);
                zacc[d] = __builtin_amdgcn_mfma_f32_16x16x32_bf16(a0, b0, zacc[d], 0, 0, 0);
                zacc[d] = __builtin_amdgcn_mfma_f32_16x16x32_bf16(a1, b1, zacc[d], 0, 0, 0);
            }
        }
    }
    int jc = col - rb4 * 4;
    #pragma unroll
    for (int d = 0; d < 5; ++d) {
        #pragma unroll
        for (int r = 0; r < 4; ++r) {
            int j = 16 * d + jc - r;
            if ((unsigned)j < 62u) atomicAdd(&dacc[wid][rb4][j], zacc[d][r]);
        }
    }
    __syncthreads();

    // ---- sigmoid ----
    if (tid < CC) {
        float dv = 0.f;
        #pragma unroll
        for (int w = 0; w < 4; ++w)
            #pragma unroll
            for (int g = 0; g < 4; ++g) dv += dacc[w][g][tid];
        adjt[tid] = 1.f / (1.f + __expf(-(dv + be + arow)));
    }
    __syncthreads();

    // ---- wx from xT bf16 (per-lane bank rotation) ----
    if (tid < 176) {
        float s = 0.f;
        if (tid < LL) {
            int xorv = (tid & 7) << 2;
            int m0 = tid % 31;
            #pragma unroll
            for (int mm = 0; mm < 31; ++mm) {
                int m = m0 + mm; if (m >= 31) m -= 31;
                unsigned v = xTu[(tid * 32 + m) ^ xorv];
                s += adjt[2 * m] * bflo(v) + adjt[2 * m + 1] * bfhi(v);
            }
        }
        wxb[(size_t)bt * 176 + tid] = s;
    }
}

// ---------------- fused G + gates: 8 bt per block ----------------
__global__ __launch_bounds__(256) void k_gg(
        const float* __restrict__ wxb, const float* __restrict__ gcnw,
        const float* __restrict__ gcnb, const float* __restrict__ WtAll,
        const float* __restrict__ bias192, float* __restrict__ gates) {
    __shared__ float wxl[8 * 176];
    __shared__ float Gl[8 * 64];
    int bt0 = blockIdx.x * 8;
    int tid = threadIdx.x;
    const float* src = wxb + (size_t)bt0 * 176;
    for (int i = tid; i < 8 * 176; i += 256) wxl[i] = src[i];
    __syncthreads();
    #pragma unroll
    for (int rep = 0; rep < 2; ++rep) {
        int i = rep * 256 + tid;
        int bl = i >> 6, f = i & 63;
        float s = gcnb[f];
        const float* wr = wxl + bl * 176;
        #pragma unroll 13
        for (int l = 0; l < LL; ++l) s += wr[l] * gcnw[l * OG + f];
        Gl[i] = s;
    }
    __syncthreads();
    float* gout = gates + (size_t)bt0 * 192;
    #pragma unroll
    for (int rep = 0; rep < 6; ++rep) {
        int i = rep * 256 + tid;
        int bl = i / 192, q = i - bl * 192;
        const float* gr = Gl + bl * 64;
        float s = bias192[q];
        #pragma unroll 16
        for (int k = 0; k < OG; ++k) s += gr[k] * WtAll[k * 192 + q];
        gout[i] = s;
    }
}

// ---------------- sequential GRU scan over t: one block per batch row ----------------
__global__ __launch_bounds__(256) void k_scan(
        const float* __restrict__ gates,
        const float* __restrict__ Wr, const float* __restrict__ Wu, const float* __restrict__ Wc,
        float* __restrict__ out) {
    __shared__ float hl[OH], rhl[OH];
    int b = blockIdx.x;
    int tid = threadIdx.x;
    int f = tid >> 2, q = tid & 3;
    float wr[16], wu[16], wc[16];
    #pragma unroll
    for (int i = 0; i < 16; ++i) {
        int col = OG + q * 16 + i;
        wr[i] = Wr[f * (OG + OH) + col];
        wu[i] = Wu[f * (OG + OH) + col];
        wc[i] = Wc[f * (OG + OH) + col];
    }
    float h = 0.f;
    if (tid < OH) hl[tid] = 0.f;
    __syncthreads();
    for (int t = 0; t < SS; ++t) {
        const float* gp = gates + ((size_t)b * SS + t) * 192;
        float gr = gp[f];
        float gu = gp[64 + f];
        float gc = gp[128 + f];
        float rv = 0.f, uv = 0.f;
        #pragma unroll
        for (int i = 0; i < 16; ++i) {
            float hv = hl[q * 16 + i];
            rv += wr[i] * hv;
            uv += wu[i] * hv;
        }
        rv += __shfl_xor(rv, 1); rv += __shfl_xor(rv, 2);
        uv += __shfl_xor(uv, 1); uv += __shfl_xor(uv, 2);
        float r = 1.f / (1.f + __expf(-(rv + gr)));
        float u = 1.f / (1.f + __expf(-(uv + gu)));
        if (q == 0) rhl[f] = r * h;
        __syncthreads();
        float cv = 0.f;
        #pragma unroll
        for (int i = 0; i < 16; ++i) cv += wc[i] * rhl[q * 16 + i];
        cv += __shfl_xor(cv, 1); cv += __shfl_xor(cv, 2);
        float cc = tanhf(cv + gc);
        if (q == 0) {
            h = u * h + (1.f - u) * cc;
            hl[f] = h;
        }
        __syncthreads();
    }
    if (q == 0) out[b * OH + f] = h;
}

extern "C" void kernel_launch(void* const* d_in, const int* in_sizes, int n_in,
                              void* d_out, int out_size, void* d_ws, size_t ws_size,
                              hipStream_t stream) {
    const float* x    = (const float*)d_in[0];
    const float* adj  = (const float*)d_in[1];
    const float* dw1w = (const float*)d_in[2];
    const float* dw1b = (const float*)d_in[3];
    const float* pw1w = (const float*)d_in[4];
    const float* pw1b = (const float*)d_in[5];
    const float* dw2w = (const float*)d_in[6];
    const float* dw2b = (const float*)d_in[7];
    const float* pw2w = (const float*)d_in[8];
    const float* pw2b = (const float*)d_in[9];
    const float* dw3w = (const float*)d_in[10];
    const float* dw3b = (const float*)d_in[11];
    const float* pw3w = (const float*)d_in[12];
    const float* pw3b = (const float*)d_in[13];
    const float* gcnw = (const float*)d_in[14];
    const float* gcnb = (const float*)d_in[15];
    const float* Wrw  = (const float*)d_in[16];
    const float* Wrb  = (const float*)d_in[17];
    const float* Wuw  = (const float*)d_in[18];
    const float* Wub  = (const float*)d_in[19];
    const float* Wcw  = (const float*)d_in[20];
    const float* Wcb  = (const float*)d_in[21];
    const float* br   = (const float*)d_in[22];
    const float* bu   = (const float*)d_in[23];
    const float* bc   = (const float*)d_in[24];
    float* out = (float*)d_out;

    char* ws = (char*)d_ws;
    unsigned short* Ftb = (unsigned short*)(ws + 0);        // 14336 B
    float* WtAll        = (float*)(ws + 14336);             // 49152 B
    float* bias192      = (float*)(ws + 63488);             // 768 B
    float* beff         = (float*)(ws + 64256);             // 4 B
    float* Bmg          = (float*)(ws + 64320);             // 11160 B
    float* wxb          = (float*)(ws + 76800);             // 5406720 B
    float* gates        = (float*)(ws + 5483520);           // 5898240 B
    (void)ws_size; (void)in_sizes; (void)n_in; (void)out_size;

    k_setup1<<<1, 1024, 0, stream>>>(dw1w, dw1b, pw1w, pw1b, dw2w, dw2b, pw2w, pw2b,
                                     dw3w, dw3b, pw3w, pw3b,
                                     Wrw, Wrb, br, Wuw, Wub, bu, Wcw, Wcb, bc,
                                     Bmg, WtAll, bias192, beff);
    k_setupF<<<64, 128, 0, stream>>>(Bmg, dw1w, Ftb);
    k_main<<<BB * SS, 256, 0, stream>>>(x, adj, Ftb, beff, wxb);
    k_gg<<<BB * SS / 8, 256, 0, stream>>>(wxb, gcnw, gcnb, WtAll, bias192, gates);
    k_scan<<<BB, 256, 0, stream>>>(gates, Wrw, Wuw, Wcw, out);
}

// Round 15
// 280.936 us; speedup vs baseline: 1.2593x; 1.0387x over previous
//
#include <hip/hip_runtime.h>
#include <math.h>

#define BB 256
#define SS 30
#define CC 62
#define LL 169
#define OG 64
#define OH 64
#define KK1 64
#define KK2 32
#define KK3 14
#define FLEN 108     // 64+32+14-2

typedef __attribute__((ext_vector_type(8))) short s16x8;
typedef __attribute__((ext_vector_type(4))) float f32x4;

__device__ __forceinline__ unsigned short f2bf(float f) {
    unsigned u = __float_as_uint(f);
    u += 0x7fffu + ((u >> 16) & 1u);        // RTNE
    return (unsigned short)(u >> 16);
}
__device__ __forceinline__ float bflo(unsigned v) { return __uint_as_float(v << 16); }
__device__ __forceinline__ float bfhi(unsigned v) { return __uint_as_float(v & 0xffff0000u); }

// ---------------- setup stage 1 (1 block): weights prep + Bm ----------------
__global__ __launch_bounds__(1024) void k_setup1(
        const float* __restrict__ dw1, const float* __restrict__ dw1b,
        const float* __restrict__ pw1, const float* __restrict__ pw1b,
        const float* __restrict__ dw2, const float* __restrict__ dw2b,
        const float* __restrict__ pw2, const float* __restrict__ pw2b,
        const float* __restrict__ dw3, const float* __restrict__ dw3b,
        const float* __restrict__ pw3, const float* __restrict__ pw3b,
        const float* __restrict__ Wr, const float* __restrict__ Wrb, const float* __restrict__ br,
        const float* __restrict__ Wu, const float* __restrict__ Wub, const float* __restrict__ bu,
        const float* __restrict__ Wc, const float* __restrict__ Wcb, const float* __restrict__ bc,
        float* __restrict__ Bmg, float* __restrict__ WtAll,
        float* __restrict__ bias192, float* __restrict__ beff) {
    __shared__ float g23[CC * KK3];
    __shared__ float Am[CC * 45];
    __shared__ float by2[CC], vals[CC];
    int tid = threadIdx.x;

    for (int idx = tid; idx < OG * 192; idx += 1024) {
        int i = idx / 192, q = idx - i * 192;
        int gate = q >> 6, f = q & 63;
        const float* W = gate == 0 ? Wr : (gate == 1 ? Wu : Wc);
        WtAll[idx] = W[f * (OG + OH) + i];
    }
    if (tid < 192) {
        int gate = tid >> 6, f = tid & 63;
        const float* Wb = gate == 0 ? Wrb : (gate == 1 ? Wub : Wcb);
        const float* bb = gate == 0 ? br  : (gate == 1 ? bu  : bc);
        bias192[tid] = Wb[f] + bb[f];
    }
    for (int idx = tid; idx < CC * KK3; idx += 1024) {
        int c1 = idx / KK3, k3 = idx - c1 * KK3;
        float s = 0.f;
        for (int c2 = 0; c2 < CC; ++c2)
            s += pw3[61 * CC + c2] * pw2[c2 * CC + c1] * dw3[c2 * KK3 + k3];
        g23[idx] = s;
    }
    if (tid < CC) {
        int c1 = tid;
        float bz1 = pw1b[c1];
        for (int c0 = 0; c0 < CC; ++c0) bz1 += pw1[c1 * CC + c0] * dw1b[c0];
        float s2 = 0.f;
        for (int k = 0; k < KK2; ++k) s2 += dw2[c1 * KK2 + k];
        by2[c1] = dw2b[c1] + bz1 * s2;
    }
    __syncthreads();
    if (tid < CC) {
        int c2 = tid;
        float bz2 = pw2b[c2];
        for (int c1 = 0; c1 < CC; ++c1) bz2 += pw2[c2 * CC + c1] * by2[c1];
        float s3 = 0.f;
        for (int k = 0; k < KK3; ++k) s3 += dw3[c2 * KK3 + k];
        vals[c2] = pw3[61 * CC + c2] * (dw3b[c2] + bz2 * s3);
    }
    for (int idx = tid; idx < CC * 45; idx += 1024) {
        int c1 = idx / 45, m = idx - c1 * 45;
        int k2lo = max(0, m - (KK3 - 1));
        int k2hi = min(KK2 - 1, m);
        float s = 0.f;
        for (int k2 = k2lo; k2 <= k2hi; ++k2)
            s += dw2[c1 * KK2 + k2] * g23[c1 * KK3 + (m - k2)];
        Am[idx] = s;
    }
    __syncthreads();
    if (tid == 0) {
        float s = pw3b[61];
        for (int c2 = 0; c2 < CC; ++c2) s += vals[c2];
        *beff = s;
    }
    for (int idx = tid; idx < CC * 45; idx += 1024) {
        int c0 = idx / 45, m = idx - c0 * 45;
        float s = 0.f;
        for (int c1 = 0; c1 < CC; ++c1) s += pw1[c1 * CC + c0] * Am[c1 * 45 + m];
        Bmg[idx] = s;
    }
}

// ---------------- setup stage 2 (64 blocks): Ftb[o][c0] ----------------
__global__ __launch_bounds__(128) void k_setupF(
        const float* __restrict__ Bmg, const float* __restrict__ dw1,
        unsigned short* __restrict__ Ftb) {
    __shared__ float Bl[45];
    int c0 = blockIdx.x;
    int o = threadIdx.x;
    if (c0 < CC && o < 45) Bl[o] = Bmg[c0 * 45 + o];
    __syncthreads();
    if (o >= 112) return;
    float s = 0.f;
    if (c0 < CC && o < FLEN) {
        int mlo = max(0, o - (KK1 - 1));
        int mhi = min(44, o);
        for (int m = mlo; m <= mhi; ++m)
            s += Bl[m] * dw1[c0 * KK1 + (o - m)];
    }
    Ftb[o * 64 + c0] = f2bf(s);
}

// ---------------- main: one block per (b,t); asm rolling staging + all-MFMA tail ----------------
#define STG_ISSUE(i, s) do {                                                   \
    const float* pA = xg + 338 * cpa[i] + l0a[i];                              \
    const float* pB = pA + 169;                                                \
    asm volatile("global_load_dwordx2 %0, %1, off" : "=v"(A0[s]) : "v"(pA));   \
    asm volatile("global_load_dwordx2 %0, %1, off" : "=v"(A1[s]) : "v"(pA + 2));\
    asm volatile("global_load_dwordx2 %0, %1, off" : "=v"(B0[s]) : "v"(pB));   \
    asm volatile("global_load_dwordx2 %0, %1, off" : "=v"(B1[s]) : "v"(pB + 2));\
} while (0)

#define STG_CONSUME(i, s, VM) do {                                             \
    asm volatile("s_waitcnt vmcnt(" VM ")"                                     \
        : "+v"(A0[s]), "+v"(A1[s]), "+v"(B0[s]), "+v"(B1[s]));                 \
    unsigned d0, d1, d2, d3;                                                   \
    asm("v_cvt_pk_bf16_f32 %0, %1, %2" : "=v"(d0)                             \
        : "v"(__uint_as_float(A0[s].x)), "v"(__uint_as_float(B0[s].x)));       \
    asm("v_cvt_pk_bf16_f32 %0, %1, %2" : "=v"(d1)                             \
        : "v"(__uint_as_float(A0[s].y)), "v"(__uint_as_float(B0[s].y)));       \
    asm("v_cvt_pk_bf16_f32 %0, %1, %2" : "=v"(d2)                             \
        : "v"(__uint_as_float(A1[s].x)), "v"(__uint_as_float(B1[s].x)));       \
    asm("v_cvt_pk_bf16_f32 %0, %1, %2" : "=v"(d3)                             \
        : "v"(__uint_as_float(A1[s].y)), "v"(__uint_as_float(B1[s].y)));       \
    int l0 = l0a[i], cp = cpa[i];                                              \
    xTu[((l0 + 0) * 32 + cp) ^ (((l0 + 0) & 7) << 2)] = d0;                    \
    xTu[((l0 + 1) * 32 + cp) ^ (((l0 + 1) & 7) << 2)] = d1;                    \
    xTu[((l0 + 2) * 32 + cp) ^ (((l0 + 2) & 7) << 2)] = d2;                    \
    xTu[((l0 + 3) * 32 + cp) ^ (((l0 + 3) & 7) << 2)] = d3;                    \
} while (0)

__global__ __launch_bounds__(256, 3) void k_main(
        const float* __restrict__ x, const float* __restrict__ adj,
        const unsigned short* __restrict__ Ftb, const float* __restrict__ beff_p,
        float* __restrict__ wxb) {
    __shared__ __align__(16) unsigned short xT[176 * 64];   // 22528 B swizzled [l][c] bf16
    __shared__ float dacc[4][64];                           // cross-wave band accumulator
    __shared__ __align__(16) unsigned adjbf[32];            // adjt packed bf16 (64 vals, pad 0)
    int bt = blockIdx.x;
    int tid = threadIdx.x;
    int lane = tid & 63, wid = tid >> 6;
    int col = lane & 15, rb4 = lane >> 4;
    unsigned* xTu = (unsigned*)xT;
    const float* xg = x + (size_t)bt * (CC * LL);

    // aux loads FIRST (older vmcnt entries -> pipeline waits stay sufficient)
    float be = *beff_p;                                        // SMEM
    float2 arow2 = make_float2(0.f, 0.f);
    if (tid < 31) arow2 = *(const float2*)(adj + 61 * CC + 2 * tid);   // 1 vmem
    const unsigned short* ap0 = Ftb + ((wid * 16 + col) * 64 + rb4 * 8);
    s16x8 pa0 = *(const s16x8*)ap0;
    s16x8 pa1 = *(const s16x8*)(ap0 + 32);
    int mt2c = wid + 4 < 7 ? wid + 4 : 6;
    const unsigned short* ap1 = Ftb + ((mt2c * 16 + col) * 64 + rb4 * 8);
    s16x8 pb0 = *(const s16x8*)ap1;
    s16x8 pb1 = *(const s16x8*)(ap1 + 32);
    __builtin_amdgcn_sched_barrier(0);

    // staging decomposition: w = lg*31 + cp; pair cp -> channels 2cp,2cp+1; 4 l's per step
    uint2 A0[3], A1[3], B0[3], B1[3];
    int l0a[6], cpa[6];
    #pragma unroll
    for (int i = 0; i < 6; ++i) {
        int w = tid + i * 256; if (w > 1332) w = 1332;
        int lg = w / 31; cpa[i] = w - lg * 31;
        l0a[i] = (lg < 42) ? 4 * lg : 165;
    }
    STG_ISSUE(0, 0); STG_ISSUE(1, 1); STG_ISSUE(2, 2);
    // overlap load latency: zero pads (col dword 31, rows>=169) + dacc
    for (int i = tid; i < 169; i += 256) xTu[(i * 32 + 31) ^ ((i & 7) << 2)] = 0;
    for (int i = tid; i < 224; i += 256) {
        int r = 169 + (i >> 5), dd = i & 31;
        xTu[(r * 32 + dd) ^ ((r & 7) << 2)] = 0;
    }
    ((float*)dacc)[tid] = 0.f;

    STG_CONSUME(0, 0, "8"); STG_ISSUE(3, 0);
    STG_CONSUME(1, 1, "8"); STG_ISSUE(4, 1);
    STG_CONSUME(2, 2, "8"); STG_ISSUE(5, 2);
    STG_CONSUME(3, 0, "8");
    STG_CONSUME(4, 1, "4");
    STG_CONSUME(5, 2, "0");
    __syncthreads();

    // ---- band MFMA: wave wid handles mt in {wid, wid+4}; atomics -> dacc[rb4][j] ----
    // NOTE: high-c half read is (bbyte ^ 64), NOT (bbyte + 64): bbyte already has the
    // row-XOR applied; pre-swizzle bit6 is 0 so +64 pre-swizzle == ^64 post-swizzle.
    f32x4 zacc[5];
    #pragma unroll
    for (int d = 0; d < 5; ++d) zacc[d] = (f32x4){0.f, 0.f, 0.f, 0.f};
    int kb = rb4 * 16;
    int xr = (lane & 7) << 4;
    #pragma unroll
    for (int h = 0; h < 2; ++h) {
        int mt = wid + 4 * h;
        if (mt < 7) {
            s16x8 a0 = h == 0 ? pa0 : pb0;
            s16x8 a1 = h == 0 ? pa1 : pb1;
            #pragma unroll
            for (int d = 0; d < 5; ++d) {
                int nt = mt + d;
                int bbyte = ((nt * 16 + col) * 128 + kb) ^ xr;
                s16x8 b0 = *(const s16x8*)((const char*)xT + bbyte);
                s16x8 b1 = *(const s16x8*)((const char*)xT + (bbyte ^ 64));
                zacc[d] = __builtin_amdgcn_mfma_f32_16x16x32_bf16(a0, b0, zacc[d], 0, 0, 0);
                zacc[d] = __builtin_amdgcn_mfma_f32_16x16x32_bf16(a1, b1, zacc[d], 0, 0, 0);
            }
        }
    }
    int jc = col - rb4 * 4;
    #pragma unroll
    for (int d = 0; d < 5; ++d) {
        #pragma unroll
        for (int r = 0; r < 4; ++r) {
            int j = 16 * d + jc - r;
            if ((unsigned)j < 62u) atomicAdd(&dacc[rb4][j], zacc[d][r]);
        }
    }
    __syncthreads();

    // ---- fused sigmoid + bf16 pack (31 threads produce the wx-MFMA A-fragment) ----
    if (tid < 32) {
        unsigned pk = 0;
        if (tid < 31) {
            int j0 = 2 * tid;
            float2 g0 = *(const float2*)(&dacc[0][j0]);
            float2 g1 = *(const float2*)(&dacc[1][j0]);
            float2 g2 = *(const float2*)(&dacc[2][j0]);
            float2 g3 = *(const float2*)(&dacc[3][j0]);
            float dv0 = (g0.x + g1.x) + (g2.x + g3.x) + be + arow2.x;
            float dv1 = (g0.y + g1.y) + (g2.y + g3.y) + be + arow2.y;
            float s0 = 1.f / (1.f + __expf(-dv0));
            float s1 = 1.f / (1.f + __expf(-dv1));
            asm("v_cvt_pk_bf16_f32 %0, %1, %2" : "=v"(pk) : "v"(s0), "v"(s1));
        }
        adjbf[tid] = pk;
    }
    __syncthreads();

    // ---- wx via MFMA: A = adjt broadcast rows; reuse xT B-fragments ----
    {
        s16x8 wa0 = *(const s16x8*)(adjbf + rb4 * 4);        // c 0..31 slice
        s16x8 wa1 = *(const s16x8*)(adjbf + 16 + rb4 * 4);   // c 32..63 slice
        #pragma unroll
        for (int q = 0; q < 3; ++q) {
            int nt = wid + 4 * q;
            if (nt < 11) {
                int bbyte = ((nt * 16 + col) * 128 + kb) ^ xr;
                s16x8 b0 = *(const s16x8*)((const char*)xT + bbyte);
                s16x8 b1 = *(const s16x8*)((const char*)xT + (bbyte ^ 64));
                f32x4 wacc = {0.f, 0.f, 0.f, 0.f};
                wacc = __builtin_amdgcn_mfma_f32_16x16x32_bf16(wa0, b0, wacc, 0, 0, 0);
                wacc = __builtin_amdgcn_mfma_f32_16x16x32_bf16(wa1, b1, wacc, 0, 0, 0);
                if (rb4 == 0) wxb[(size_t)bt * 176 + nt * 16 + col] = wacc[0];
            }
        }
    }
}

// ---------------- fused G + gates: 8 bt per block ----------------
__global__ __launch_bounds__(256) void k_gg(
        const float* __restrict__ wxb, const float* __restrict__ gcnw,
        const float* __restrict__ gcnb, const float* __restrict__ WtAll,
        const float* __restrict__ bias192, float* __restrict__ gates) {
    __shared__ float wxl[8 * 176];
    __shared__ float Gl[8 * 64];
    int bt0 = blockIdx.x * 8;
    int tid = threadIdx.x;
    const float* src = wxb + (size_t)bt0 * 176;
    for (int i = tid; i < 8 * 176; i += 256) wxl[i] = src[i];
    __syncthreads();
    #pragma unroll
    for (int rep = 0; rep < 2; ++rep) {
        int i = rep * 256 + tid;
        int bl = i >> 6, f = i & 63;
        float s = gcnb[f];
        const float* wr = wxl + bl * 176;
        #pragma unroll 13
        for (int l = 0; l < LL; ++l) s += wr[l] * gcnw[l * OG + f];
        Gl[i] = s;
    }
    __syncthreads();
    float* gout = gates + (size_t)bt0 * 192;
    #pragma unroll
    for (int rep = 0; rep < 6; ++rep) {
        int i = rep * 256 + tid;
        int bl = i / 192, q = i - bl * 192;
        const float* gr = Gl + bl * 64;
        float s = bias192[q];
        #pragma unroll 16
        for (int k = 0; k < OG; ++k) s += gr[k] * WtAll[k * 192 + q];
        gout[i] = s;
    }
}

// ---------------- sequential GRU scan over t: one block per batch row ----------------
__global__ __launch_bounds__(256) void k_scan(
        const float* __restrict__ gates,
        const float* __restrict__ Wr, const float* __restrict__ Wu, const float* __restrict__ Wc,
        float* __restrict__ out) {
    __shared__ float hl[OH], rhl[OH];
    int b = blockIdx.x;
    int tid = threadIdx.x;
    int f = tid >> 2, q = tid & 3;
    float wr[16], wu[16], wc[16];
    #pragma unroll
    for (int i = 0; i < 16; ++i) {
        int col = OG + q * 16 + i;
        wr[i] = Wr[f * (OG + OH) + col];
        wu[i] = Wu[f * (OG + OH) + col];
        wc[i] = Wc[f * (OG + OH) + col];
    }
    float h = 0.f;
    if (tid < OH) hl[tid] = 0.f;
    __syncthreads();
    for (int t = 0; t < SS; ++t) {
        const float* gp = gates + ((size_t)b * SS + t) * 192;
        float gr = gp[f];
        float gu = gp[64 + f];
        float gc = gp[128 + f];
        float rv = 0.f, uv = 0.f;
        #pragma unroll
        for (int i = 0; i < 16; ++i) {
            float hv = hl[q * 16 + i];
            rv += wr[i] * hv;
            uv += wu[i] * hv;
        }
        rv += __shfl_xor(rv, 1); rv += __shfl_xor(rv, 2);
        uv += __shfl_xor(uv, 1); uv += __shfl_xor(uv, 2);
        float r = 1.f / (1.f + __expf(-(rv + gr)));
        float u = 1.f / (1.f + __expf(-(uv + gu)));
        if (q == 0) rhl[f] = r * h;
        __syncthreads();
        float cv = 0.f;
        #pragma unroll
        for (int i = 0; i < 16; ++i) cv += wc[i] * rhl[q * 16 + i];
        cv += __shfl_xor(cv, 1); cv += __shfl_xor(cv, 2);
        float cc = tanhf(cv + gc);
        if (q == 0) {
            h = u * h + (1.f - u) * cc;
            hl[f] = h;
        }
        __syncthreads();
    }
    if (q == 0) out[b * OH + f] = h;
}

extern "C" void kernel_launch(void* const* d_in, const int* in_sizes, int n_in,
                              void* d_out, int out_size, void* d_ws, size_t ws_size,
                              hipStream_t stream) {
    const float* x    = (const float*)d_in[0];
    const float* adj  = (const float*)d_in[1];
    const float* dw1w = (const float*)d_in[2];
    const float* dw1b = (const float*)d_in[3];
    const float* pw1w = (const float*)d_in[4];
    const float* pw1b = (const float*)d_in[5];
    const float* dw2w = (const float*)d_in[6];
    const float* dw2b = (const float*)d_in[7];
    const float* pw2w = (const float*)d_in[8];
    const float* pw2b = (const float*)d_in[9];
    const float* dw3w = (const float*)d_in[10];
    const float* dw3b = (const float*)d_in[11];
    const float* pw3w = (const float*)d_in[12];
    const float* pw3b = (const float*)d_in[13];
    const float* gcnw = (const float*)d_in[14];
    const float* gcnb = (const float*)d_in[15];
    const float* Wrw  = (const float*)d_in[16];
    const float* Wrb  = (const float*)d_in[17];
    const float* Wuw  = (const float*)d_in[18];
    const float* Wub  = (const float*)d_in[19];
    const float* Wcw  = (const float*)d_in[20];
    const float* Wcb  = (const float*)d_in[21];
    const float* br   = (const float*)d_in[22];
    const float* bu   = (const float*)d_in[23];
    const float* bc   = (const float*)d_in[24];
    float* out = (float*)d_out;

    char* ws = (char*)d_ws;
    unsigned short* Ftb = (unsigned short*)(ws + 0);        // 14336 B
    float* WtAll        = (float*)(ws + 14336);             // 49152 B
    float* bias192      = (float*)(ws + 63488);             // 768 B
    float* beff         = (float*)(ws + 64256);             // 4 B
    float* Bmg          = (float*)(ws + 64320);             // 11160 B
    float* wxb          = (float*)(ws + 76800);             // 5406720 B
    float* gates        = (float*)(ws + 5483520);           // 5898240 B
    (void)ws_size; (void)in_sizes; (void)n_in; (void)out_size;

    k_setup1<<<1, 1024, 0, stream>>>(dw1w, dw1b, pw1w, pw1b, dw2w, dw2b, pw2w, pw2b,
                                     dw3w, dw3b, pw3w, pw3b,
                                     Wrw, Wrb, br, Wuw, Wub, bu, Wcw, Wcb, bc,
                                     Bmg, WtAll, bias192, beff);
    k_setupF<<<64, 128, 0, stream>>>(Bmg, dw1w, Ftb);
    k_main<<<BB * SS, 256, 0, stream>>>(x, adj, Ftb, beff, wxb);
    k_gg<<<BB * SS / 8, 256, 0, stream>>>(wxb, gcnw, gcnb, WtAll, bias192, gates);
    k_scan<<<BB, 256, 0, stream>>>(gates, Wrw, Wuw, Wcw, out);
}